// Round 12
// baseline (94.813 us; speedup 1.0000x reference)
//
#include <hip/hip_runtime.h>
#include <hip/hip_bf16.h>
#include <math.h>

typedef __attribute__((ext_vector_type(16))) float f32x16;
typedef __attribute__((ext_vector_type(8))) short short8;
typedef __attribute__((ext_vector_type(4))) short short4v;
typedef __attribute__((ext_vector_type(4))) unsigned uint4v;

#define BATCH 32
#define SEQ 1024
#define DIM 128
#define NBLK 512
#define TILE_BYTES 16384
#define CDOT 0.02254211097f       // 2 * log2(e) / 128
#define SQE_SCALE 0.011271055485f // log2(e) / 128

__device__ __forceinline__ float exp2f_fast(float x) {
  float r;
  asm("v_exp_f32 %0, %1" : "=v"(r) : "v"(x));
  return r;
}

__device__ __forceinline__ unsigned cvt_pk_bf16(float lo, float hi) {
  unsigned r;
  asm("v_cvt_pk_bf16_f32 %0, %1, %2" : "=v"(r) : "v"(lo), "v"(hi));
  return r;
}

// N-layout: byte offset of (j, k) in 64x128 bf16 tile: [k>>4][j][k&15],
// 16B-half XOR swizzle keyed on (j>>2)&1.
__device__ __forceinline__ unsigned vs_off(int j, int k) {
  return ((unsigned)(k >> 4) << 11) + ((unsigned)j << 5)
       + ((((unsigned)(k & 15)) << 1) ^ ((((unsigned)j >> 2) & 1) << 4));
}

__device__ __forceinline__ short4v ds_tr16(unsigned addr) {
  short4v r;
  asm volatile("ds_read_b64_tr_b16 %0, %1" : "=v"(r) : "v"(addr));
  return r;
}

typedef __attribute__((address_space(1))) const unsigned int gu32;
typedef __attribute__((address_space(3))) unsigned int lu32;
__device__ __forceinline__ void gload_lds16(const void* g, void* l) {
  __builtin_amdgcn_global_load_lds((gu32*)g, (lu32*)l, 16, 0, 0);
}

// ---- prepack: f32 -> bf16 tiles in N layout + sq*log2e/128 ----
__global__ __launch_bounds__(256)
void prepack_kernel(const float* __restrict__ clip, const float* __restrict__ sent,
                    char* __restrict__ outN, float* __restrict__ sqe_all) {
  const int bid = blockIdx.x;   // 1024 tiles: 512 clip then 512 sent
  const int tid = threadIdx.x;
  const float* inp = (bid < NBLK) ? clip : sent;
  const size_t row0 = (size_t)(bid & (NBLK - 1)) * 64;
  char* ot = outN + (size_t)bid * TILE_BYTES;
  #pragma unroll
  for (int it = 0; it < 8; ++it) {
    int idx = it * 256 + tid;
    int j = idx >> 5, q = idx & 31;
    float4 v = *reinterpret_cast<const float4*>(inp + (row0 + j) * DIM + q * 4);
    uint2 pk;
    pk.x = cvt_pk_bf16(v.x, v.y);
    pk.y = cvt_pk_bf16(v.z, v.w);
    *reinterpret_cast<uint2*>(ot + vs_off(j, q * 4)) = pk;
    float s = v.x * v.x + v.y * v.y + v.z * v.z + v.w * v.w;
    #pragma unroll
    for (int off = 1; off < 32; off <<= 1) s += __shfl_xor(s, off);
    if ((tid & 31) == 0) sqe_all[bid * 64 + j] = s * SQE_SCALE;
  }
}

// ---------------- fused per-cycle kernel ----------------
// 256-thread blocks (4 waves = 2 pairs). Each PAIR owns 64 q-rows; wave h of a
// pair processes j-half h of every KV tile. KV tiles are PAIR-PRIVATE; each
// wave stages AND reads only its own j-half (tr-read address span verified to
// stay inside the half) -> NO in-loop barriers; counted s_waitcnt vmcnt(8)
// keeps next-tile loads in flight. One barrier separates the main loop from
// the pair-merge (which reuses the dead VS buffer as scratch).
__global__ __launch_bounds__(256, 2)
void cycle_kernel(const char* __restrict__ embN, const float* __restrict__ sqe_all,
                  const float* __restrict__ clip_lens, const float* __restrict__ sent_lens,
                  float* __restrict__ partials)
{
  __shared__ __align__(16) char VSall[65536];        // 2 pairs x 2 bufs x 16KB
  __shared__ __align__(16) float SQL[2][SEQ];        // sqe broadcast (oth, src)
  __shared__ float RED[4][4][64];                    // scalar-exchange scratch

  const int tid = threadIdx.x;
  const int x = blockIdx.x;                          // 512 blocks
  // bijective remap: co-resident blocks (x, x+256) share (b,cyc) -> identical
  // trip counts (no half-occupancy tail); low 3 bits spread batches over XCDs.
  const int rest = x >> 3;
  const int b    = (x & 7) + 8 * ((rest >> 2) & 3);
  const int cyc  = (rest >> 4) & 1;
  const int qh   = (rest & 3) | (((rest >> 5) & 1) << 2);

  const char* srcN = embN + (cyc ? (size_t)NBLK * TILE_BYTES : 0);
  const char* othN = embN + (cyc ? 0 : (size_t)NBLK * TILE_BYTES);
  const float* sqe_src = sqe_all + (cyc ? BATCH * SEQ : 0) + b * SEQ;
  const float* sqe_oth = sqe_all + (cyc ? 0 : BATCH * SEQ) + b * SEQ;
  const float* lens_src = cyc ? sent_lens : clip_lens;
  const float* lens_oth = cyc ? clip_lens : sent_lens;

  const int w = tid >> 6, l = tid & 63;
  const int p = w >> 1, h = w & 1;                   // pair, j-half
  const int il = l & 31, hi = l >> 5, g1 = (l >> 4) & 1;

  char* const vsp = VSall + p * 32768;               // this pair's two buffers

  const char* src_tiles = srcN + (size_t)(b * 16) * TILE_BYTES;
  const char* oth_tiles = othN + (size_t)(b * 16) * TILE_BYTES;

  const int nv1 = (int)(lens_oth[b] + 0.5f);
  const int nv2 = (int)(lens_src[b] + 0.5f);
  const int nt1 = (nv1 + 63) >> 6;
  const int nt2 = (nv2 + 63) >> 6;

  // wave stages ONLY its own j-half (full-tile byte offsets preserved)
  auto STAGE = [&](int buf, const char* gt) {
    #pragma unroll
    for (int i = 0; i < 8; ++i) {
      const int off = i * 2048 + h * 1024 + l * 16;
      gload_lds16(gt + off, vsp + buf * 16384 + off);
    }
  };

  STAGE(0, oth_tiles);
  {
    float4 vo = reinterpret_cast<const float4*>(sqe_oth)[tid];
    float4 vq = reinterpret_cast<const float4*>(sqe_src)[tid];
    reinterpret_cast<float4*>(&SQL[0][0])[tid] = vo;
    reinterpret_cast<float4*>(&SQL[1][0])[tid] = vq;
  }

  // per-lane byte offsets
  const unsigned qk0 = (unsigned)(il * 32 + ((hi * 16) ^ (((il >> 2) & 1) << 4)));
  const int t16 = (l & 8) ? -16 : 16;   // swizzle compensation for second tr-read

  // Q B-fragments: pair p owns q-tile (qh*2 + p); set s rows = s*32 + il
  short8 aq[2][8];
  {
    const char* qt = src_tiles + (size_t)(qh * 2 + p) * TILE_BYTES;
    #pragma unroll
    for (int s = 0; s < 2; ++s) {
      const unsigned qoff = (unsigned)((s * 32 + il) * 32
                            + ((hi * 16) ^ (((il >> 2) & 1) << 4)));
      #pragma unroll
      for (int kc = 0; kc < 8; ++kc)
        aq[s][kc] = *reinterpret_cast<const short8*>(qt + qoff + kc * 2048);
    }
  }

  f32x16 nn[2][4];   // nn^T[dblk*32 + crow(r,hi)][set*32 + il], this wave's j-half
  #pragma unroll
  for (int s = 0; s < 2; ++s)
    #pragma unroll
    for (int d = 0; d < 4; ++d)
      #pragma unroll
      for (int r = 0; r < 16; ++r) nn[s][d][r] = 0.f;
  float lsum[2] = {0.f, 0.f};

  __syncthreads();   // SQL visibility + drain prologue loads (vmcnt -> 0)

  // ================= stage 1: src vs oth, nn accumulated via MFMA =================
  int cur = 0;
  for (int t = 0; t < nt1; ++t) {
    const int jb = t * 64;
    if (t + 1 < nt1) STAGE(cur ^ 1, oth_tiles + (size_t)(t + 1) * TILE_BYTES);
    else             STAGE(cur ^ 1, src_tiles);       // prefetch stage-2 tile 0
    // wait for THIS tile's loads (8 newest stay in flight); in-order retirement
    asm volatile("s_waitcnt vmcnt(8)" ::: "memory");

    const char* vsc = vsp + cur * 16384;
    const unsigned vsb = (unsigned)(size_t)vsc;
    const unsigned trb0 = vsb + (unsigned)(g1 * 1920);
    const unsigned trb1 = trb0 + (unsigned)(128 + t16);
    const bool partial = (jb + h * 32 + 32) > nv1;

    // swapped QK^T on this wave's j-half; both q-sets share every K fragment
    f32x16 sa0, sa1;
    #pragma unroll
    for (int r = 0; r < 16; ++r) { sa0[r] = 0.f; sa1[r] = 0.f; }
    __builtin_amdgcn_s_setprio(1);
    #pragma unroll
    for (int kc = 0; kc < 8; ++kc) {
      short8 ka = *reinterpret_cast<const short8*>(vsc + qk0 + h * 1024 + kc * 2048);
      sa0 = __builtin_amdgcn_mfma_f32_32x32x16_bf16(ka, aq[0][kc], sa0, 0, 0, 0);
      sa1 = __builtin_amdgcn_mfma_f32_32x32x16_bf16(ka, aq[1][kc], sa1, 0, 0, 0);
    }
    __builtin_amdgcn_s_setprio(0);
    #pragma unroll
    for (int q = 0; q < 4; ++q) {
      float4 sq4 = *reinterpret_cast<const float4*>(&SQL[0][jb + h * 32 + q * 8 + hi * 4]);
      sa0[q*4+0] = exp2f_fast(fmaf(sa0[q*4+0], CDOT, -sq4.x));
      sa0[q*4+1] = exp2f_fast(fmaf(sa0[q*4+1], CDOT, -sq4.y));
      sa0[q*4+2] = exp2f_fast(fmaf(sa0[q*4+2], CDOT, -sq4.z));
      sa0[q*4+3] = exp2f_fast(fmaf(sa0[q*4+3], CDOT, -sq4.w));
      sa1[q*4+0] = exp2f_fast(fmaf(sa1[q*4+0], CDOT, -sq4.x));
      sa1[q*4+1] = exp2f_fast(fmaf(sa1[q*4+1], CDOT, -sq4.y));
      sa1[q*4+2] = exp2f_fast(fmaf(sa1[q*4+2], CDOT, -sq4.z));
      sa1[q*4+3] = exp2f_fast(fmaf(sa1[q*4+3], CDOT, -sq4.w));
    }
    if (partial) {
      #pragma unroll
      for (int r = 0; r < 16; ++r) {
        int j = jb + h * 32 + (r & 3) + 8 * (r >> 2) + 4 * hi;
        if (j >= nv1) { sa0[r] = 0.f; sa1[r] = 0.f; }
      }
    }
    float ls0 = 0.f, ls1 = 0.f;
    #pragma unroll
    for (int r = 0; r < 16; ++r) { ls0 += sa0[r]; ls1 += sa1[r]; }
    lsum[0] += ls0; lsum[1] += ls1;

    // ---- PV per gm: tr-reads issue, pack under their latency (R8 reg peak) ----
    #pragma unroll
    for (int gm = 0; gm < 2; ++gm) {
      const int kap = h * 2 + gm;
      short4v t0[4], t1[4];
      #pragma unroll
      for (int dblk = 0; dblk < 4; ++dblk) {
        t0[dblk] = ds_tr16(trb0 + (unsigned)(dblk * 4096 + kap * 512));
        t1[dblk] = ds_tr16(trb1 + (unsigned)(dblk * 4096 + kap * 512));
      }
      unsigned a00 = cvt_pk_bf16(sa0[gm*8+0], sa0[gm*8+1]);
      unsigned a01 = cvt_pk_bf16(sa0[gm*8+2], sa0[gm*8+3]);
      unsigned a10 = cvt_pk_bf16(sa0[gm*8+4], sa0[gm*8+5]);
      unsigned a11 = cvt_pk_bf16(sa0[gm*8+6], sa0[gm*8+7]);
      asm volatile("v_permlane32_swap_b32 %0, %1" : "+v"(a00), "+v"(a10));
      asm volatile("v_permlane32_swap_b32 %0, %1" : "+v"(a01), "+v"(a11));
      uint4v pw0; pw0.x = a00; pw0.y = a01; pw0.z = a10; pw0.w = a11;
      short8 paf0 = __builtin_bit_cast(short8, pw0);
      unsigned b00 = cvt_pk_bf16(sa1[gm*8+0], sa1[gm*8+1]);
      unsigned b01 = cvt_pk_bf16(sa1[gm*8+2], sa1[gm*8+3]);
      unsigned b10 = cvt_pk_bf16(sa1[gm*8+4], sa1[gm*8+5]);
      unsigned b11 = cvt_pk_bf16(sa1[gm*8+6], sa1[gm*8+7]);
      asm volatile("v_permlane32_swap_b32 %0, %1" : "+v"(b00), "+v"(b10));
      asm volatile("v_permlane32_swap_b32 %0, %1" : "+v"(b01), "+v"(b11));
      uint4v pw1; pw1.x = b00; pw1.y = b01; pw1.z = b10; pw1.w = b11;
      short8 paf1 = __builtin_bit_cast(short8, pw1);

      asm volatile("s_waitcnt lgkmcnt(0)" ::: "memory");
      __builtin_amdgcn_sched_barrier(0);
      __builtin_amdgcn_s_setprio(1);
      #pragma unroll
      for (int dblk = 0; dblk < 4; ++dblk) {
        short8 vf = __builtin_shufflevector(t0[dblk], t1[dblk], 0, 1, 2, 3, 4, 5, 6, 7);
        nn[0][dblk] = __builtin_amdgcn_mfma_f32_32x32x16_bf16(vf, paf0, nn[0][dblk], 0, 0, 0);
        nn[1][dblk] = __builtin_amdgcn_mfma_f32_32x32x16_bf16(vf, paf1, nn[1][dblk], 0, 0, 0);
      }
      __builtin_amdgcn_s_setprio(0);
    }
    cur ^= 1;   // no barrier: each wave reads only what it staged
  }

  // ---- BARRIER: sibling wave may still be computing from the buffer we are
  // about to reuse as merge scratch (its j-half lives inside our 8KB region).
  __syncthreads();

  // ---- pair-merge: sum nn and lsum across the two j-half waves.
  // Scratch = the pair's DEAD buffer (cur^1); buffer cur holds stage-2 prefetch.
  RED[w][0][l] = lsum[0];
  RED[w][1][l] = lsum[1];
  char* const mg_self = vsp + (cur ^ 1) * 16384 + h * 8192;
  const char* const mg_peer = vsp + (cur ^ 1) * 16384 + (h ^ 1) * 8192;
  #pragma unroll
  for (int c = 0; c < 4; ++c) {
    const int s = c >> 1, d0 = (c & 1) * 2;
    #pragma unroll
    for (int hf = 0; hf < 2; ++hf) {
      const f32x16 v = nn[s][d0 + hf];
      #pragma unroll
      for (int i = 0; i < 4; ++i) {
        float4 f4;
        f4.x = v[i*4+0]; f4.y = v[i*4+1]; f4.z = v[i*4+2]; f4.w = v[i*4+3];
        *reinterpret_cast<float4*>(mg_self + (hf * 4 + i) * 1024 + l * 16) = f4;
      }
    }
    __syncthreads();
    #pragma unroll
    for (int hf = 0; hf < 2; ++hf) {
      #pragma unroll
      for (int i = 0; i < 4; ++i) {
        float4 f4 = *reinterpret_cast<const float4*>(
            mg_peer + (hf * 4 + i) * 1024 + l * 16);
        nn[s][d0+hf][i*4+0] += f4.x;
        nn[s][d0+hf][i*4+1] += f4.y;
        nn[s][d0+hf][i*4+2] += f4.z;
        nn[s][d0+hf][i*4+3] += f4.w;
      }
    }
    __syncthreads();
  }
  lsum[0] += RED[w ^ 1][0][l];
  lsum[1] += RED[w ^ 1][1][l];

  // ---- normalize nn, convert to stage-2 B-frags in-register (identical in pair)
  short8 aq2[2][8];
  #pragma unroll
  for (int s = 0; s < 2; ++s) {
    lsum[s] += __shfl_xor(lsum[s], 32);
    const float inv1 = 1.f / lsum[s];
    #pragma unroll
    for (int kc = 0; kc < 8; ++kc) {
      const int dblk = kc >> 1, gm = kc & 1;
      unsigned u00 = cvt_pk_bf16(nn[s][dblk][gm*8+0] * inv1, nn[s][dblk][gm*8+1] * inv1);
      unsigned u01 = cvt_pk_bf16(nn[s][dblk][gm*8+2] * inv1, nn[s][dblk][gm*8+3] * inv1);
      unsigned u10 = cvt_pk_bf16(nn[s][dblk][gm*8+4] * inv1, nn[s][dblk][gm*8+5] * inv1);
      unsigned u11 = cvt_pk_bf16(nn[s][dblk][gm*8+6] * inv1, nn[s][dblk][gm*8+7] * inv1);
      asm volatile("v_permlane32_swap_b32 %0, %1" : "+v"(u00), "+v"(u10));
      asm volatile("v_permlane32_swap_b32 %0, %1" : "+v"(u01), "+v"(u11));
      uint4v pw; pw.x = u00; pw.y = u01; pw.z = u10; pw.w = u11;
      aq2[s][kc] = __builtin_bit_cast(short8, pw);
    }
  }

  // ================= stage 2: nn vs src originals, weighted index =================
  float l2s[2] = {0.f, 0.f}, ixs[2] = {0.f, 0.f};
  for (int t = 0; t < nt2; ++t) {
    const int jb = t * 64;
    if (t + 1 < nt2) {
      STAGE(cur ^ 1, src_tiles + (size_t)(t + 1) * TILE_BYTES);
      asm volatile("s_waitcnt vmcnt(8)" ::: "memory");
    } else {
      asm volatile("s_waitcnt vmcnt(0)" ::: "memory");
    }

    const char* vsc = vsp + cur * 16384;
    const bool partial = (jb + h * 32 + 32) > nv2;

    f32x16 sa0, sa1;
    #pragma unroll
    for (int r = 0; r < 16; ++r) { sa0[r] = 0.f; sa1[r] = 0.f; }
    __builtin_amdgcn_s_setprio(1);
    #pragma unroll
    for (int kc = 0; kc < 8; ++kc) {
      short8 ka = *reinterpret_cast<const short8*>(vsc + qk0 + h * 1024 + kc * 2048);
      sa0 = __builtin_amdgcn_mfma_f32_32x32x16_bf16(ka, aq2[0][kc], sa0, 0, 0, 0);
      sa1 = __builtin_amdgcn_mfma_f32_32x32x16_bf16(ka, aq2[1][kc], sa1, 0, 0, 0);
    }
    __builtin_amdgcn_s_setprio(0);
    #pragma unroll
    for (int q = 0; q < 4; ++q) {
      float4 sq4 = *reinterpret_cast<const float4*>(&SQL[1][jb + h * 32 + q * 8 + hi * 4]);
      sa0[q*4+0] = exp2f_fast(fmaf(sa0[q*4+0], CDOT, -sq4.x));
      sa0[q*4+1] = exp2f_fast(fmaf(sa0[q*4+1], CDOT, -sq4.y));
      sa0[q*4+2] = exp2f_fast(fmaf(sa0[q*4+2], CDOT, -sq4.z));
      sa0[q*4+3] = exp2f_fast(fmaf(sa0[q*4+3], CDOT, -sq4.w));
      sa1[q*4+0] = exp2f_fast(fmaf(sa1[q*4+0], CDOT, -sq4.x));
      sa1[q*4+1] = exp2f_fast(fmaf(sa1[q*4+1], CDOT, -sq4.y));
      sa1[q*4+2] = exp2f_fast(fmaf(sa1[q*4+2], CDOT, -sq4.z));
      sa1[q*4+3] = exp2f_fast(fmaf(sa1[q*4+3], CDOT, -sq4.w));
    }
    if (partial) {
      #pragma unroll
      for (int r = 0; r < 16; ++r) {
        int j = jb + h * 32 + (r & 3) + 8 * (r >> 2) + 4 * hi;
        if (j >= nv2) { sa0[r] = 0.f; sa1[r] = 0.f; }
      }
    }
    #pragma unroll
    for (int r = 0; r < 16; ++r) {
      float jc = (float)(jb + h * 32 + (r & 3) + 8 * (r >> 2) + 4 * hi);
      l2s[0] += sa0[r];
      l2s[1] += sa1[r];
      ixs[0] = fmaf(sa0[r], jc, ixs[0]);
      ixs[1] = fmaf(sa1[r], jc, ixs[1]);
    }
    cur ^= 1;   // no barrier
  }

  // ---- pair-merge scalars, then per-q loss ----
  RED[w][0][l] = l2s[0]; RED[w][1][l] = l2s[1];
  RED[w][2][l] = ixs[0]; RED[w][3][l] = ixs[1];
  __syncthreads();
  l2s[0] += RED[w ^ 1][0][l]; l2s[1] += RED[w ^ 1][1][l];
  ixs[0] += RED[w ^ 1][2][l]; ixs[1] += RED[w ^ 1][3][l];

  float acc = 0.f;
  #pragma unroll
  for (int s = 0; s < 2; ++s) {
    l2s[s] += __shfl_xor(l2s[s], 32);
    ixs[s] += __shfl_xor(ixs[s], 32);
    int iabs = qh * 128 + p * 64 + s * 32 + il;
    float diff = ixs[s] / l2s[s] - (float)iabs;
    acc += (iabs < nv2) ? diff * diff : 0.f;
  }
  #pragma unroll
  for (int off = 1; off < 32; off <<= 1) acc += __shfl_xor(acc, off);
  if (h == 0 && l == 0)
    partials[cyc * 512 + (b * 8 + qh) * 2 + p] = acc / ((float)nv2 * (float)BATCH);
}

// ---------------- deterministic final reduction ----------------
__global__ void reduce_kernel(const float* __restrict__ partials, float* __restrict__ out) {
  __shared__ float red[256];
  const int c = blockIdx.x;
  float s = 0.f;
  for (int i = threadIdx.x; i < 512; i += 256) s += partials[c * 512 + i];
  red[threadIdx.x] = s;
  __syncthreads();
  for (int off = 128; off > 0; off >>= 1) {
    if (threadIdx.x < off) red[threadIdx.x] += red[threadIdx.x + off];
    __syncthreads();
  }
  if (threadIdx.x == 0) out[c] = red[0];
}

extern "C" void kernel_launch(void* const* d_in, const int* in_sizes, int n_in,
                              void* d_out, int out_size, void* d_ws, size_t ws_size,
                              hipStream_t stream) {
  const float* clip_emb  = (const float*)d_in[0];
  const float* clip_lens = (const float*)d_in[2];
  const float* sent_emb  = (const float*)d_in[3];
  const float* sent_lens = (const float*)d_in[5];
  float* out = (float*)d_out;
  char* wsb = (char*)d_ws;

  char*  embN    = wsb;                                            // 16 MB N tiles
  float* sqe_all = (float*)(wsb + 2 * (size_t)NBLK * TILE_BYTES);  // 64K floats
  float* parts   = sqe_all + 2 * BATCH * SEQ;                      // 1024 floats

  prepack_kernel<<<2 * NBLK, 256, 0, stream>>>(clip_emb, sent_emb, embN, sqe_all);
  cycle_kernel<<<NBLK, 256, 0, stream>>>(embN, sqe_all, clip_lens, sent_lens, parts);
  reduce_kernel<<<2, 256, 0, stream>>>(parts, out);
}

// Round 13
// 77.255 us; speedup vs baseline: 1.2273x; 1.2273x over previous
//
#include <hip/hip_runtime.h>
#include <hip/hip_bf16.h>
#include <math.h>

typedef __attribute__((ext_vector_type(16))) float f32x16;
typedef __attribute__((ext_vector_type(8))) short short8;
typedef __attribute__((ext_vector_type(4))) short short4v;
typedef __attribute__((ext_vector_type(4))) unsigned uint4v;

#define BATCH 32
#define SEQ 1024
#define DIM 128
#define NBLK 512
#define TILE_BYTES 16384
#define CDOT 0.02254211097f       // 2 * log2(e) / 128
#define SQE_SCALE 0.011271055485f // log2(e) / 128

__device__ __forceinline__ float exp2f_fast(float x) {
  float r;
  asm("v_exp_f32 %0, %1" : "=v"(r) : "v"(x));
  return r;
}

__device__ __forceinline__ unsigned cvt_pk_bf16(float lo, float hi) {
  unsigned r;
  asm("v_cvt_pk_bf16_f32 %0, %1, %2" : "=v"(r) : "v"(lo), "v"(hi));
  return r;
}

// N-layout: byte offset of (j, k) in 64x128 bf16 tile: [k>>4][j][k&15],
// 16B-half XOR swizzle keyed on (j>>2)&1.
__device__ __forceinline__ unsigned vs_off(int j, int k) {
  return ((unsigned)(k >> 4) << 11) + ((unsigned)j << 5)
       + ((((unsigned)(k & 15)) << 1) ^ ((((unsigned)j >> 2) & 1) << 4));
}

__device__ __forceinline__ short4v ds_tr16(unsigned addr) {
  short4v r;
  asm volatile("ds_read_b64_tr_b16 %0, %1" : "=v"(r) : "v"(addr));
  return r;
}

typedef __attribute__((address_space(1))) const unsigned int gu32;
typedef __attribute__((address_space(3))) unsigned int lu32;
__device__ __forceinline__ void gload_lds16(const void* g, void* l) {
  __builtin_amdgcn_global_load_lds((gu32*)g, (lu32*)l, 16, 0, 0);
}

// ---- prepack: f32 -> bf16 tiles in N layout + sq*log2e/128 ----
__global__ __launch_bounds__(256)
void prepack_kernel(const float* __restrict__ clip, const float* __restrict__ sent,
                    char* __restrict__ outN, float* __restrict__ sqe_all) {
  const int bid = blockIdx.x;   // 1024 tiles: 512 clip then 512 sent
  const int tid = threadIdx.x;
  const float* inp = (bid < NBLK) ? clip : sent;
  const size_t row0 = (size_t)(bid & (NBLK - 1)) * 64;
  char* ot = outN + (size_t)bid * TILE_BYTES;
  #pragma unroll
  for (int it = 0; it < 8; ++it) {
    int idx = it * 256 + tid;
    int j = idx >> 5, q = idx & 31;
    float4 v = *reinterpret_cast<const float4*>(inp + (row0 + j) * DIM + q * 4);
    uint2 pk;
    pk.x = cvt_pk_bf16(v.x, v.y);
    pk.y = cvt_pk_bf16(v.z, v.w);
    *reinterpret_cast<uint2*>(ot + vs_off(j, q * 4)) = pk;
    float s = v.x * v.x + v.y * v.y + v.z * v.z + v.w * v.w;
    #pragma unroll
    for (int off = 1; off < 32; off <<= 1) s += __shfl_xor(s, off);
    if ((tid & 31) == 0) sqe_all[bid * 64 + j] = s * SQE_SCALE;
  }
}

// ---------------- fused per-cycle kernel ----------------
// 256-thread blocks (4 waves = 2 pairs). Each PAIR owns 64 q-rows; wave h
// processes j-half h. R8 body verbatim; KV staged TWO tiles (32 KB) per
// iteration so the vmcnt(0)+barrier cost is paid once per 128 j (half of R8).
// Pair-merge reuses the dead 32 KB VS buffer as scratch.
__global__ __launch_bounds__(256, 2)
void cycle_kernel(const char* __restrict__ embN, const float* __restrict__ sqe_all,
                  const float* __restrict__ clip_lens, const float* __restrict__ sent_lens,
                  float* __restrict__ partials)
{
  __shared__ __align__(16) char VS[2][32768];        // double-buffered 2-tile KV step
  __shared__ __align__(16) float SQL[2][SEQ];        // sqe broadcast (oth, src)
  __shared__ float RED[4][4][64];                    // scalar-exchange scratch

  const int tid = threadIdx.x;
  const int x = blockIdx.x;                          // 512 blocks
  // bijective remap: co-resident blocks (x, x+256) share (b,cyc) -> identical
  // trip counts (no half-occupancy tail); low 3 bits spread batches over XCDs.
  const int rest = x >> 3;
  const int b    = (x & 7) + 8 * ((rest >> 2) & 3);
  const int cyc  = (rest >> 4) & 1;
  const int qh   = (rest & 3) | (((rest >> 5) & 1) << 2);

  const char* srcN = embN + (cyc ? (size_t)NBLK * TILE_BYTES : 0);
  const char* othN = embN + (cyc ? 0 : (size_t)NBLK * TILE_BYTES);
  const float* sqe_src = sqe_all + (cyc ? BATCH * SEQ : 0) + b * SEQ;
  const float* sqe_oth = sqe_all + (cyc ? 0 : BATCH * SEQ) + b * SEQ;
  const float* lens_src = cyc ? sent_lens : clip_lens;
  const float* lens_oth = cyc ? clip_lens : sent_lens;

  const int w = tid >> 6, l = tid & 63;
  const int p = w >> 1, h = w & 1;                   // pair, j-half
  const int il = l & 31, hi = l >> 5, g1 = (l >> 4) & 1;

  const char* src_tiles = srcN + (size_t)(b * 16) * TILE_BYTES;
  const char* oth_tiles = othN + (size_t)(b * 16) * TILE_BYTES;

  const int nv1 = (int)(lens_oth[b] + 0.5f);
  const int nv2 = (int)(lens_src[b] + 0.5f);
  const int nt1_2 = (nv1 + 127) >> 7;                // 128-j steps
  const int nt2_2 = (nv2 + 127) >> 7;

  // stage a 32 KB double-tile: 8 x 4 KB slabs, linear (layout matches global)
  auto STAGE = [&](int buf, const char* gt) {
    #pragma unroll
    for (int i = 0; i < 8; ++i)
      gload_lds16(gt + i * 4096 + tid * 16, &VS[buf][i * 4096 + tid * 16]);
  };

  STAGE(0, oth_tiles);
  {
    float4 vo = reinterpret_cast<const float4*>(sqe_oth)[tid];
    float4 vq = reinterpret_cast<const float4*>(sqe_src)[tid];
    reinterpret_cast<float4*>(&SQL[0][0])[tid] = vo;
    reinterpret_cast<float4*>(&SQL[1][0])[tid] = vq;
  }

  // per-lane byte offsets
  const unsigned qk0 = (unsigned)(il * 32 + ((hi * 16) ^ (((il >> 2) & 1) << 4)));
  const int t16 = (l & 8) ? -16 : 16;   // swizzle compensation for second tr-read

  // Q B-fragments: pair p owns q-tile (qh*2 + p); set s rows = s*32 + il
  short8 aq[2][8];
  {
    const char* qt = src_tiles + (size_t)(qh * 2 + p) * TILE_BYTES;
    #pragma unroll
    for (int s = 0; s < 2; ++s) {
      const unsigned qoff = (unsigned)((s * 32 + il) * 32
                            + ((hi * 16) ^ (((il >> 2) & 1) << 4)));
      #pragma unroll
      for (int kc = 0; kc < 8; ++kc)
        aq[s][kc] = *reinterpret_cast<const short8*>(qt + qoff + kc * 2048);
    }
  }

  f32x16 nn[2][4];   // nn^T[dblk*32 + crow(r,hi)][set*32 + il], this wave's j-half
  #pragma unroll
  for (int s = 0; s < 2; ++s)
    #pragma unroll
    for (int d = 0; d < 4; ++d)
      #pragma unroll
      for (int r = 0; r < 16; ++r) nn[s][d][r] = 0.f;
  float lsum[2] = {0.f, 0.f};

  asm volatile("s_waitcnt vmcnt(0)" ::: "memory");
  __syncthreads();

  // ================= stage 1: src vs oth, nn accumulated via MFMA =================
  int cur = 0;
  for (int t = 0; t < nt1_2; ++t) {
    if (t + 1 < nt1_2) STAGE(cur ^ 1, oth_tiles + (size_t)(t + 1) * 32768);
    else               STAGE(cur ^ 1, src_tiles);     // prefetch stage-2 step 0

    #pragma unroll
    for (int sub = 0; sub < 2; ++sub) {
      const int jb = t * 128 + sub * 64;
      if (jb < nv1) {
        const char* vsc = &VS[cur][0] + sub * 16384;
        const unsigned vsb = (unsigned)(size_t)vsc;
        const unsigned trb0 = vsb + (unsigned)(g1 * 1920);
        const unsigned trb1 = trb0 + (unsigned)(128 + t16);
        const bool partial = (jb + h * 32 + 32) > nv1;

        // swapped QK^T on this wave's j-half; both q-sets share every K frag
        f32x16 sa0, sa1;
        #pragma unroll
        for (int r = 0; r < 16; ++r) { sa0[r] = 0.f; sa1[r] = 0.f; }
        #pragma unroll
        for (int kc = 0; kc < 8; ++kc) {
          short8 ka = *reinterpret_cast<const short8*>(vsc + qk0 + h * 1024 + kc * 2048);
          sa0 = __builtin_amdgcn_mfma_f32_32x32x16_bf16(ka, aq[0][kc], sa0, 0, 0, 0);
          sa1 = __builtin_amdgcn_mfma_f32_32x32x16_bf16(ka, aq[1][kc], sa1, 0, 0, 0);
        }
        #pragma unroll
        for (int q = 0; q < 4; ++q) {
          float4 sq4 = *reinterpret_cast<const float4*>(&SQL[0][jb + h * 32 + q * 8 + hi * 4]);
          sa0[q*4+0] = exp2f_fast(fmaf(sa0[q*4+0], CDOT, -sq4.x));
          sa0[q*4+1] = exp2f_fast(fmaf(sa0[q*4+1], CDOT, -sq4.y));
          sa0[q*4+2] = exp2f_fast(fmaf(sa0[q*4+2], CDOT, -sq4.z));
          sa0[q*4+3] = exp2f_fast(fmaf(sa0[q*4+3], CDOT, -sq4.w));
          sa1[q*4+0] = exp2f_fast(fmaf(sa1[q*4+0], CDOT, -sq4.x));
          sa1[q*4+1] = exp2f_fast(fmaf(sa1[q*4+1], CDOT, -sq4.y));
          sa1[q*4+2] = exp2f_fast(fmaf(sa1[q*4+2], CDOT, -sq4.z));
          sa1[q*4+3] = exp2f_fast(fmaf(sa1[q*4+3], CDOT, -sq4.w));
        }
        if (partial) {
          #pragma unroll
          for (int r = 0; r < 16; ++r) {
            int j = jb + h * 32 + (r & 3) + 8 * (r >> 2) + 4 * hi;
            if (j >= nv1) { sa0[r] = 0.f; sa1[r] = 0.f; }
          }
        }
        float ls0 = 0.f, ls1 = 0.f;
        #pragma unroll
        for (int r = 0; r < 16; ++r) { ls0 += sa0[r]; ls1 += sa1[r]; }
        lsum[0] += ls0; lsum[1] += ls1;

        // PV per gm: pack P B-frags, tr-read V^T A-frags, MFMA (R8 order)
        #pragma unroll
        for (int gm = 0; gm < 2; ++gm) {
          const int kap = h * 2 + gm;
          unsigned a00 = cvt_pk_bf16(sa0[gm*8+0], sa0[gm*8+1]);
          unsigned a01 = cvt_pk_bf16(sa0[gm*8+2], sa0[gm*8+3]);
          unsigned a10 = cvt_pk_bf16(sa0[gm*8+4], sa0[gm*8+5]);
          unsigned a11 = cvt_pk_bf16(sa0[gm*8+6], sa0[gm*8+7]);
          asm volatile("v_permlane32_swap_b32 %0, %1" : "+v"(a00), "+v"(a10));
          asm volatile("v_permlane32_swap_b32 %0, %1" : "+v"(a01), "+v"(a11));
          uint4v pw0; pw0.x = a00; pw0.y = a01; pw0.z = a10; pw0.w = a11;
          short8 paf0 = __builtin_bit_cast(short8, pw0);
          unsigned b00 = cvt_pk_bf16(sa1[gm*8+0], sa1[gm*8+1]);
          unsigned b01 = cvt_pk_bf16(sa1[gm*8+2], sa1[gm*8+3]);
          unsigned b10 = cvt_pk_bf16(sa1[gm*8+4], sa1[gm*8+5]);
          unsigned b11 = cvt_pk_bf16(sa1[gm*8+6], sa1[gm*8+7]);
          asm volatile("v_permlane32_swap_b32 %0, %1" : "+v"(b00), "+v"(b10));
          asm volatile("v_permlane32_swap_b32 %0, %1" : "+v"(b01), "+v"(b11));
          uint4v pw1; pw1.x = b00; pw1.y = b01; pw1.z = b10; pw1.w = b11;
          short8 paf1 = __builtin_bit_cast(short8, pw1);

          short4v t0[4], t1[4];
          #pragma unroll
          for (int dblk = 0; dblk < 4; ++dblk) {
            t0[dblk] = ds_tr16(trb0 + (unsigned)(dblk * 4096 + kap * 512));
            t1[dblk] = ds_tr16(trb1 + (unsigned)(dblk * 4096 + kap * 512));
          }
          asm volatile("s_waitcnt lgkmcnt(0)" ::: "memory");
          __builtin_amdgcn_sched_barrier(0);
          #pragma unroll
          for (int dblk = 0; dblk < 4; ++dblk) {
            short8 vf = __builtin_shufflevector(t0[dblk], t1[dblk], 0, 1, 2, 3, 4, 5, 6, 7);
            nn[0][dblk] = __builtin_amdgcn_mfma_f32_32x32x16_bf16(vf, paf0, nn[0][dblk], 0, 0, 0);
            nn[1][dblk] = __builtin_amdgcn_mfma_f32_32x32x16_bf16(vf, paf1, nn[1][dblk], 0, 0, 0);
          }
        }
      }
    }

    asm volatile("s_waitcnt vmcnt(0)" ::: "memory");
    __syncthreads();
    cur ^= 1;
  }

  // ---- pair-merge: sum nn and lsum across the two j-half waves.
  // Scratch = dead VS buffer (cur^1, 32 KB); VS[cur] holds stage-2 prefetch.
  RED[w][0][l] = lsum[0];
  RED[w][1][l] = lsum[1];
  char* const mg = &VS[cur ^ 1][0];
  #pragma unroll
  for (int c = 0; c < 4; ++c) {
    const int s = c >> 1, d0 = (c & 1) * 2;
    #pragma unroll
    for (int hf = 0; hf < 2; ++hf) {
      const f32x16 v = nn[s][d0 + hf];
      #pragma unroll
      for (int i = 0; i < 4; ++i) {
        float4 f4;
        f4.x = v[i*4+0]; f4.y = v[i*4+1]; f4.z = v[i*4+2]; f4.w = v[i*4+3];
        *reinterpret_cast<float4*>(mg + w * 8192 + (hf * 4 + i) * 1024 + l * 16) = f4;
      }
    }
    __syncthreads();
    #pragma unroll
    for (int hf = 0; hf < 2; ++hf) {
      #pragma unroll
      for (int i = 0; i < 4; ++i) {
        float4 f4 = *reinterpret_cast<const float4*>(
            mg + (w ^ 1) * 8192 + (hf * 4 + i) * 1024 + l * 16);
        nn[s][d0+hf][i*4+0] += f4.x;
        nn[s][d0+hf][i*4+1] += f4.y;
        nn[s][d0+hf][i*4+2] += f4.z;
        nn[s][d0+hf][i*4+3] += f4.w;
      }
    }
    __syncthreads();
  }
  lsum[0] += RED[w ^ 1][0][l];
  lsum[1] += RED[w ^ 1][1][l];

  // ---- normalize nn, convert to stage-2 B-frags in-register (identical in pair)
  short8 aq2[2][8];
  #pragma unroll
  for (int s = 0; s < 2; ++s) {
    lsum[s] += __shfl_xor(lsum[s], 32);
    const float inv1 = 1.f / lsum[s];
    #pragma unroll
    for (int kc = 0; kc < 8; ++kc) {
      const int dblk = kc >> 1, gm = kc & 1;
      unsigned u00 = cvt_pk_bf16(nn[s][dblk][gm*8+0] * inv1, nn[s][dblk][gm*8+1] * inv1);
      unsigned u01 = cvt_pk_bf16(nn[s][dblk][gm*8+2] * inv1, nn[s][dblk][gm*8+3] * inv1);
      unsigned u10 = cvt_pk_bf16(nn[s][dblk][gm*8+4] * inv1, nn[s][dblk][gm*8+5] * inv1);
      unsigned u11 = cvt_pk_bf16(nn[s][dblk][gm*8+6] * inv1, nn[s][dblk][gm*8+7] * inv1);
      asm volatile("v_permlane32_swap_b32 %0, %1" : "+v"(u00), "+v"(u10));
      asm volatile("v_permlane32_swap_b32 %0, %1" : "+v"(u01), "+v"(u11));
      uint4v pw; pw.x = u00; pw.y = u01; pw.z = u10; pw.w = u11;
      aq2[s][kc] = __builtin_bit_cast(short8, pw);
    }
  }

  // ================= stage 2: nn vs src originals, weighted index =================
  float l2s[2] = {0.f, 0.f}, ixs[2] = {0.f, 0.f};
  for (int t = 0; t < nt2_2; ++t) {
    if (t + 1 < nt2_2) STAGE(cur ^ 1, src_tiles + (size_t)(t + 1) * 32768);

    #pragma unroll
    for (int sub = 0; sub < 2; ++sub) {
      const int jb = t * 128 + sub * 64;
      if (jb < nv2) {
        const char* vsc = &VS[cur][0] + sub * 16384;
        const bool partial = (jb + h * 32 + 32) > nv2;

        f32x16 sa0, sa1;
        #pragma unroll
        for (int r = 0; r < 16; ++r) { sa0[r] = 0.f; sa1[r] = 0.f; }
        #pragma unroll
        for (int kc = 0; kc < 8; ++kc) {
          short8 ka = *reinterpret_cast<const short8*>(vsc + qk0 + h * 1024 + kc * 2048);
          sa0 = __builtin_amdgcn_mfma_f32_32x32x16_bf16(ka, aq2[0][kc], sa0, 0, 0, 0);
          sa1 = __builtin_amdgcn_mfma_f32_32x32x16_bf16(ka, aq2[1][kc], sa1, 0, 0, 0);
        }
        #pragma unroll
        for (int q = 0; q < 4; ++q) {
          float4 sq4 = *reinterpret_cast<const float4*>(&SQL[1][jb + h * 32 + q * 8 + hi * 4]);
          sa0[q*4+0] = exp2f_fast(fmaf(sa0[q*4+0], CDOT, -sq4.x));
          sa0[q*4+1] = exp2f_fast(fmaf(sa0[q*4+1], CDOT, -sq4.y));
          sa0[q*4+2] = exp2f_fast(fmaf(sa0[q*4+2], CDOT, -sq4.z));
          sa0[q*4+3] = exp2f_fast(fmaf(sa0[q*4+3], CDOT, -sq4.w));
          sa1[q*4+0] = exp2f_fast(fmaf(sa1[q*4+0], CDOT, -sq4.x));
          sa1[q*4+1] = exp2f_fast(fmaf(sa1[q*4+1], CDOT, -sq4.y));
          sa1[q*4+2] = exp2f_fast(fmaf(sa1[q*4+2], CDOT, -sq4.z));
          sa1[q*4+3] = exp2f_fast(fmaf(sa1[q*4+3], CDOT, -sq4.w));
        }
        if (partial) {
          #pragma unroll
          for (int r = 0; r < 16; ++r) {
            int j = jb + h * 32 + (r & 3) + 8 * (r >> 2) + 4 * hi;
            if (j >= nv2) { sa0[r] = 0.f; sa1[r] = 0.f; }
          }
        }
        #pragma unroll
        for (int r = 0; r < 16; ++r) {
          float jc = (float)(jb + h * 32 + (r & 3) + 8 * (r >> 2) + 4 * hi);
          l2s[0] += sa0[r];
          l2s[1] += sa1[r];
          ixs[0] = fmaf(sa0[r], jc, ixs[0]);
          ixs[1] = fmaf(sa1[r], jc, ixs[1]);
        }
      }
    }

    asm volatile("s_waitcnt vmcnt(0)" ::: "memory");
    __syncthreads();
    cur ^= 1;
  }

  // ---- pair-merge scalars, then per-q loss ----
  RED[w][0][l] = l2s[0]; RED[w][1][l] = l2s[1];
  RED[w][2][l] = ixs[0]; RED[w][3][l] = ixs[1];
  __syncthreads();
  l2s[0] += RED[w ^ 1][0][l]; l2s[1] += RED[w ^ 1][1][l];
  ixs[0] += RED[w ^ 1][2][l]; ixs[1] += RED[w ^ 1][3][l];

  float acc = 0.f;
  #pragma unroll
  for (int s = 0; s < 2; ++s) {
    l2s[s] += __shfl_xor(l2s[s], 32);
    ixs[s] += __shfl_xor(ixs[s], 32);
    int iabs = qh * 128 + p * 64 + s * 32 + il;
    float diff = ixs[s] / l2s[s] - (float)iabs;
    acc += (iabs < nv2) ? diff * diff : 0.f;
  }
  #pragma unroll
  for (int off = 1; off < 32; off <<= 1) acc += __shfl_xor(acc, off);
  if (h == 0 && l == 0)
    partials[cyc * 512 + (b * 8 + qh) * 2 + p] = acc / ((float)nv2 * (float)BATCH);
}

// ---------------- deterministic final reduction ----------------
__global__ void reduce_kernel(const float* __restrict__ partials, float* __restrict__ out) {
  __shared__ float red[256];
  const int c = blockIdx.x;
  float s = 0.f;
  for (int i = threadIdx.x; i < 512; i += 256) s += partials[c * 512 + i];
  red[threadIdx.x] = s;
  __syncthreads();
  for (int off = 128; off > 0; off >>= 1) {
    if (threadIdx.x < off) red[threadIdx.x] += red[threadIdx.x + off];
    __syncthreads();
  }
  if (threadIdx.x == 0) out[c] = red[0];
}

extern "C" void kernel_launch(void* const* d_in, const int* in_sizes, int n_in,
                              void* d_out, int out_size, void* d_ws, size_t ws_size,
                              hipStream_t stream) {
  const float* clip_emb  = (const float*)d_in[0];
  const float* clip_lens = (const float*)d_in[2];
  const float* sent_emb  = (const float*)d_in[3];
  const float* sent_lens = (const float*)d_in[5];
  float* out = (float*)d_out;
  char* wsb = (char*)d_ws;

  char*  embN    = wsb;                                            // 16 MB N tiles
  float* sqe_all = (float*)(wsb + 2 * (size_t)NBLK * TILE_BYTES);  // 64K floats
  float* parts   = sqe_all + 2 * BATCH * SEQ;                      // 1024 floats

  prepack_kernel<<<2 * NBLK, 256, 0, stream>>>(clip_emb, sent_emb, embN, sqe_all);
  cycle_kernel<<<NBLK, 256, 0, stream>>>(embN, sqe_all, clip_lens, sent_lens, parts);
  reduce_kernel<<<2, 256, 0, stream>>>(parts, out);
}

// Round 14
// 67.949 us; speedup vs baseline: 1.3953x; 1.1370x over previous
//
#include <hip/hip_runtime.h>
#include <hip/hip_bf16.h>
#include <math.h>

typedef __attribute__((ext_vector_type(16))) float f32x16;
typedef __attribute__((ext_vector_type(8))) short short8;
typedef __attribute__((ext_vector_type(4))) short short4v;
typedef __attribute__((ext_vector_type(4))) unsigned uint4v;

#define BATCH 32
#define SEQ 1024
#define DIM 128
#define NBLK 512
#define TILE_BYTES 16384
#define CDOT 0.02254211097f       // 2 * log2(e) / 128
#define SQE_SCALE 0.011271055485f // log2(e) / 128

__device__ __forceinline__ float exp2f_fast(float x) {
  float r;
  asm("v_exp_f32 %0, %1" : "=v"(r) : "v"(x));
  return r;
}

__device__ __forceinline__ unsigned cvt_pk_bf16(float lo, float hi) {
  unsigned r;
  asm("v_cvt_pk_bf16_f32 %0, %1, %2" : "=v"(r) : "v"(lo), "v"(hi));
  return r;
}

// N-layout: byte offset of (j, k) in 64x128 bf16 tile: [k>>4][j][k&15],
// 16B-half XOR swizzle keyed on (j>>2)&1.
__device__ __forceinline__ unsigned vs_off(int j, int k) {
  return ((unsigned)(k >> 4) << 11) + ((unsigned)j << 5)
       + ((((unsigned)(k & 15)) << 1) ^ ((((unsigned)j >> 2) & 1) << 4));
}

__device__ __forceinline__ short4v ds_tr16(unsigned addr) {
  short4v r;
  asm volatile("ds_read_b64_tr_b16 %0, %1" : "=v"(r) : "v"(addr));
  return r;
}

typedef __attribute__((address_space(1))) const unsigned int gu32;
typedef __attribute__((address_space(3))) unsigned int lu32;
__device__ __forceinline__ void gload_lds16(const void* g, void* l) {
  __builtin_amdgcn_global_load_lds((gu32*)g, (lu32*)l, 16, 0, 0);
}

// ---- prepack: f32 -> bf16 tiles in N layout + sq*log2e/128 ----
__global__ __launch_bounds__(256)
void prepack_kernel(const float* __restrict__ clip, const float* __restrict__ sent,
                    char* __restrict__ outN, float* __restrict__ sqe_all) {
  const int bid = blockIdx.x;   // 1024 tiles: 512 clip then 512 sent
  const int tid = threadIdx.x;
  const float* inp = (bid < NBLK) ? clip : sent;
  const size_t row0 = (size_t)(bid & (NBLK - 1)) * 64;
  char* ot = outN + (size_t)bid * TILE_BYTES;
  #pragma unroll
  for (int it = 0; it < 8; ++it) {
    int idx = it * 256 + tid;
    int j = idx >> 5, q = idx & 31;
    float4 v = *reinterpret_cast<const float4*>(inp + (row0 + j) * DIM + q * 4);
    uint2 pk;
    pk.x = cvt_pk_bf16(v.x, v.y);
    pk.y = cvt_pk_bf16(v.z, v.w);
    *reinterpret_cast<uint2*>(ot + vs_off(j, q * 4)) = pk;
    float s = v.x * v.x + v.y * v.y + v.z * v.z + v.w * v.w;
    #pragma unroll
    for (int off = 1; off < 32; off <<= 1) s += __shfl_xor(s, off);
    if ((tid & 31) == 0) sqe_all[bid * 64 + j] = s * SQE_SCALE;
  }
}

// ---------------- fused per-cycle kernel ----------------
// 256-thread blocks (4 waves = 2 pairs). Each PAIR owns 64 q-rows (2 stationary
// Q-sets per wave, same rows in both waves); within a pair, wave h processes
// j-half h of every KV tile. Reuse = 64 q per streamed fragment, while keeping
// grid 512 -> 2 blocks/CU -> 2 waves/SIMD.  (R8 configuration — verified best.)
__global__ __launch_bounds__(256, 2)
void cycle_kernel(const char* __restrict__ embN, const float* __restrict__ sqe_all,
                  const float* __restrict__ clip_lens, const float* __restrict__ sent_lens,
                  float* __restrict__ partials)
{
  __shared__ __align__(16) char VS[2][TILE_BYTES];   // double-buffered KV tile (N layout)
  __shared__ __align__(16) float SQL[2][SEQ];        // sqe broadcast (oth, src)
  __shared__ __align__(16) char MG[32768];           // pair-merge scratch (8KB/wave)
  __shared__ float RED[4][4][64];                    // scalar-exchange scratch

  const int tid = threadIdx.x;
  const int x = blockIdx.x;                          // 512 blocks
  const int b   = (x & 7) + 8 * (x >> 7);            // 4 batches per XCD
  const int sub = (x >> 3) & 15;
  const int cyc = sub >> 3;
  const int qh  = sub & 7;                           // 8 q-blocks of 128 rows

  const char* srcN = embN + (cyc ? (size_t)NBLK * TILE_BYTES : 0);
  const char* othN = embN + (cyc ? 0 : (size_t)NBLK * TILE_BYTES);
  const float* sqe_src = sqe_all + (cyc ? BATCH * SEQ : 0) + b * SEQ;
  const float* sqe_oth = sqe_all + (cyc ? 0 : BATCH * SEQ) + b * SEQ;
  const float* lens_src = cyc ? sent_lens : clip_lens;
  const float* lens_oth = cyc ? clip_lens : sent_lens;

  const int w = tid >> 6, l = tid & 63;
  const int p = w >> 1, h = w & 1;                   // pair, j-half
  const int il = l & 31, hi = l >> 5, g1 = (l >> 4) & 1;

  const char* src_tiles = srcN + (size_t)(b * 16) * TILE_BYTES;
  const char* oth_tiles = othN + (size_t)(b * 16) * TILE_BYTES;

  const int nv1 = (int)(lens_oth[b] + 0.5f);
  const int nv2 = (int)(lens_src[b] + 0.5f);
  const int nt1 = (nv1 + 63) >> 6;
  const int nt2 = (nv2 + 63) >> 6;

  auto STAGE = [&](int buf, const char* gt) {
    #pragma unroll
    for (int i = 0; i < 4; ++i)
      gload_lds16(gt + i * 4096 + tid * 16, &VS[buf][i * 4096 + tid * 16]);
  };

  STAGE(0, oth_tiles);
  {
    float4 vo = reinterpret_cast<const float4*>(sqe_oth)[tid];
    float4 vq = reinterpret_cast<const float4*>(sqe_src)[tid];
    reinterpret_cast<float4*>(&SQL[0][0])[tid] = vo;
    reinterpret_cast<float4*>(&SQL[1][0])[tid] = vq;
  }

  // per-lane byte offsets
  const unsigned qk0 = (unsigned)(il * 32 + ((hi * 16) ^ (((il >> 2) & 1) << 4)));
  const int t16 = (l & 8) ? -16 : 16;   // swizzle compensation for second tr-read

  // Q B-fragments: pair p owns q-tile (qh*2 + p); set s rows = s*32 + il
  short8 aq[2][8];
  {
    const char* qt = src_tiles + (size_t)(qh * 2 + p) * TILE_BYTES;
    #pragma unroll
    for (int s = 0; s < 2; ++s) {
      const unsigned qoff = (unsigned)((s * 32 + il) * 32
                            + ((hi * 16) ^ (((il >> 2) & 1) << 4)));
      #pragma unroll
      for (int kc = 0; kc < 8; ++kc)
        aq[s][kc] = *reinterpret_cast<const short8*>(qt + qoff + kc * 2048);
    }
  }

  f32x16 nn[2][4];   // nn^T[dblk*32 + crow(r,hi)][set*32 + il], this wave's j-half
  #pragma unroll
  for (int s = 0; s < 2; ++s)
    #pragma unroll
    for (int d = 0; d < 4; ++d)
      #pragma unroll
      for (int r = 0; r < 16; ++r) nn[s][d][r] = 0.f;
  float lsum[2] = {0.f, 0.f};

  asm volatile("s_waitcnt vmcnt(0)" ::: "memory");
  __syncthreads();

  // ================= stage 1: src vs oth, nn accumulated via MFMA =================
  int cur = 0;
  for (int t = 0; t < nt1; ++t) {
    const int jb = t * 64;
    if (t + 1 < nt1) STAGE(cur ^ 1, oth_tiles + (size_t)(t + 1) * TILE_BYTES);
    else             STAGE(cur ^ 1, src_tiles);       // prefetch stage-2 tile 0

    const char* vsc = &VS[cur][0];
    const unsigned vsb = (unsigned)(size_t)vsc;
    const unsigned trb0 = vsb + (unsigned)(g1 * 1920);
    const unsigned trb1 = trb0 + (unsigned)(128 + t16);
    const bool partial = (jb + h * 32 + 32) > nv1;

    // swapped QK^T on this wave's j-half; both q-sets share every K fragment
    f32x16 sa0, sa1;
    #pragma unroll
    for (int r = 0; r < 16; ++r) { sa0[r] = 0.f; sa1[r] = 0.f; }
    #pragma unroll
    for (int kc = 0; kc < 8; ++kc) {
      short8 ka = *reinterpret_cast<const short8*>(vsc + qk0 + h * 1024 + kc * 2048);
      sa0 = __builtin_amdgcn_mfma_f32_32x32x16_bf16(ka, aq[0][kc], sa0, 0, 0, 0);
      sa1 = __builtin_amdgcn_mfma_f32_32x32x16_bf16(ka, aq[1][kc], sa1, 0, 0, 0);
    }
    #pragma unroll
    for (int q = 0; q < 4; ++q) {
      float4 sq4 = *reinterpret_cast<const float4*>(&SQL[0][jb + h * 32 + q * 8 + hi * 4]);
      sa0[q*4+0] = exp2f_fast(fmaf(sa0[q*4+0], CDOT, -sq4.x));
      sa0[q*4+1] = exp2f_fast(fmaf(sa0[q*4+1], CDOT, -sq4.y));
      sa0[q*4+2] = exp2f_fast(fmaf(sa0[q*4+2], CDOT, -sq4.z));
      sa0[q*4+3] = exp2f_fast(fmaf(sa0[q*4+3], CDOT, -sq4.w));
      sa1[q*4+0] = exp2f_fast(fmaf(sa1[q*4+0], CDOT, -sq4.x));
      sa1[q*4+1] = exp2f_fast(fmaf(sa1[q*4+1], CDOT, -sq4.y));
      sa1[q*4+2] = exp2f_fast(fmaf(sa1[q*4+2], CDOT, -sq4.z));
      sa1[q*4+3] = exp2f_fast(fmaf(sa1[q*4+3], CDOT, -sq4.w));
    }
    if (partial) {
      #pragma unroll
      for (int r = 0; r < 16; ++r) {
        int j = jb + h * 32 + (r & 3) + 8 * (r >> 2) + 4 * hi;
        if (j >= nv1) { sa0[r] = 0.f; sa1[r] = 0.f; }
      }
    }
    float ls0 = 0.f, ls1 = 0.f;
    #pragma unroll
    for (int r = 0; r < 16; ++r) { ls0 += sa0[r]; ls1 += sa1[r]; }
    lsum[0] += ls0; lsum[1] += ls1;

    // per 16-j block: build P B-frags in-register; V^T A-frags shared by both sets
    #pragma unroll
    for (int gm = 0; gm < 2; ++gm) {
      const int kap = h * 2 + gm;
      unsigned a00 = cvt_pk_bf16(sa0[gm*8+0], sa0[gm*8+1]);
      unsigned a01 = cvt_pk_bf16(sa0[gm*8+2], sa0[gm*8+3]);
      unsigned a10 = cvt_pk_bf16(sa0[gm*8+4], sa0[gm*8+5]);
      unsigned a11 = cvt_pk_bf16(sa0[gm*8+6], sa0[gm*8+7]);
      asm volatile("v_permlane32_swap_b32 %0, %1" : "+v"(a00), "+v"(a10));
      asm volatile("v_permlane32_swap_b32 %0, %1" : "+v"(a01), "+v"(a11));
      uint4v pw0; pw0.x = a00; pw0.y = a01; pw0.z = a10; pw0.w = a11;
      short8 paf0 = __builtin_bit_cast(short8, pw0);
      unsigned b00 = cvt_pk_bf16(sa1[gm*8+0], sa1[gm*8+1]);
      unsigned b01 = cvt_pk_bf16(sa1[gm*8+2], sa1[gm*8+3]);
      unsigned b10 = cvt_pk_bf16(sa1[gm*8+4], sa1[gm*8+5]);
      unsigned b11 = cvt_pk_bf16(sa1[gm*8+6], sa1[gm*8+7]);
      asm volatile("v_permlane32_swap_b32 %0, %1" : "+v"(b00), "+v"(b10));
      asm volatile("v_permlane32_swap_b32 %0, %1" : "+v"(b01), "+v"(b11));
      uint4v pw1; pw1.x = b00; pw1.y = b01; pw1.z = b10; pw1.w = b11;
      short8 paf1 = __builtin_bit_cast(short8, pw1);

      short4v t0[4], t1[4];
      #pragma unroll
      for (int dblk = 0; dblk < 4; ++dblk) {
        t0[dblk] = ds_tr16(trb0 + (unsigned)(dblk * 4096 + kap * 512));
        t1[dblk] = ds_tr16(trb1 + (unsigned)(dblk * 4096 + kap * 512));
      }
      asm volatile("s_waitcnt lgkmcnt(0)" ::: "memory");
      __builtin_amdgcn_sched_barrier(0);
      #pragma unroll
      for (int dblk = 0; dblk < 4; ++dblk) {
        short8 vf = __builtin_shufflevector(t0[dblk], t1[dblk], 0, 1, 2, 3, 4, 5, 6, 7);
        nn[0][dblk] = __builtin_amdgcn_mfma_f32_32x32x16_bf16(vf, paf0, nn[0][dblk], 0, 0, 0);
        nn[1][dblk] = __builtin_amdgcn_mfma_f32_32x32x16_bf16(vf, paf1, nn[1][dblk], 0, 0, 0);
      }
    }

    asm volatile("s_waitcnt vmcnt(0)" ::: "memory");
    __syncthreads();
    cur ^= 1;
  }

  // ---- pair-merge: sum nn and lsum across the two j-half waves (both get the sum)
  RED[w][0][l] = lsum[0];
  RED[w][1][l] = lsum[1];
  #pragma unroll
  for (int c = 0; c < 4; ++c) {
    const int s = c >> 1, d0 = (c & 1) * 2;
    #pragma unroll
    for (int hf = 0; hf < 2; ++hf) {
      const f32x16 v = nn[s][d0 + hf];
      #pragma unroll
      for (int i = 0; i < 4; ++i) {
        float4 f4;
        f4.x = v[i*4+0]; f4.y = v[i*4+1]; f4.z = v[i*4+2]; f4.w = v[i*4+3];
        *reinterpret_cast<float4*>(MG + w * 8192 + (hf * 4 + i) * 1024 + l * 16) = f4;
      }
    }
    __syncthreads();
    #pragma unroll
    for (int hf = 0; hf < 2; ++hf) {
      #pragma unroll
      for (int i = 0; i < 4; ++i) {
        float4 f4 = *reinterpret_cast<const float4*>(
            MG + (w ^ 1) * 8192 + (hf * 4 + i) * 1024 + l * 16);
        nn[s][d0+hf][i*4+0] += f4.x;
        nn[s][d0+hf][i*4+1] += f4.y;
        nn[s][d0+hf][i*4+2] += f4.z;
        nn[s][d0+hf][i*4+3] += f4.w;
      }
    }
    __syncthreads();
  }
  lsum[0] += RED[w ^ 1][0][l];
  lsum[1] += RED[w ^ 1][1][l];

  // ---- normalize nn, convert to stage-2 B-frags in-register (identical in pair)
  short8 aq2[2][8];
  #pragma unroll
  for (int s = 0; s < 2; ++s) {
    lsum[s] += __shfl_xor(lsum[s], 32);
    const float inv1 = 1.f / lsum[s];
    #pragma unroll
    for (int kc = 0; kc < 8; ++kc) {
      const int dblk = kc >> 1, gm = kc & 1;
      unsigned u00 = cvt_pk_bf16(nn[s][dblk][gm*8+0] * inv1, nn[s][dblk][gm*8+1] * inv1);
      unsigned u01 = cvt_pk_bf16(nn[s][dblk][gm*8+2] * inv1, nn[s][dblk][gm*8+3] * inv1);
      unsigned u10 = cvt_pk_bf16(nn[s][dblk][gm*8+4] * inv1, nn[s][dblk][gm*8+5] * inv1);
      unsigned u11 = cvt_pk_bf16(nn[s][dblk][gm*8+6] * inv1, nn[s][dblk][gm*8+7] * inv1);
      asm volatile("v_permlane32_swap_b32 %0, %1" : "+v"(u00), "+v"(u10));
      asm volatile("v_permlane32_swap_b32 %0, %1" : "+v"(u01), "+v"(u11));
      uint4v pw; pw.x = u00; pw.y = u01; pw.z = u10; pw.w = u11;
      aq2[s][kc] = __builtin_bit_cast(short8, pw);
    }
  }

  // ================= stage 2: nn vs src originals, weighted index =================
  float l2s[2] = {0.f, 0.f}, ixs[2] = {0.f, 0.f};
  for (int t = 0; t < nt2; ++t) {
    const int jb = t * 64;
    if (t + 1 < nt2) STAGE(cur ^ 1, src_tiles + (size_t)(t + 1) * TILE_BYTES);

    const char* vsc = &VS[cur][0];
    const bool partial = (jb + h * 32 + 32) > nv2;

    f32x16 sa0, sa1;
    #pragma unroll
    for (int r = 0; r < 16; ++r) { sa0[r] = 0.f; sa1[r] = 0.f; }
    #pragma unroll
    for (int kc = 0; kc < 8; ++kc) {
      short8 ka = *reinterpret_cast<const short8*>(vsc + qk0 + h * 1024 + kc * 2048);
      sa0 = __builtin_amdgcn_mfma_f32_32x32x16_bf16(ka, aq2[0][kc], sa0, 0, 0, 0);
      sa1 = __builtin_amdgcn_mfma_f32_32x32x16_bf16(ka, aq2[1][kc], sa1, 0, 0, 0);
    }
    #pragma unroll
    for (int q = 0; q < 4; ++q) {
      float4 sq4 = *reinterpret_cast<const float4*>(&SQL[1][jb + h * 32 + q * 8 + hi * 4]);
      sa0[q*4+0] = exp2f_fast(fmaf(sa0[q*4+0], CDOT, -sq4.x));
      sa0[q*4+1] = exp2f_fast(fmaf(sa0[q*4+1], CDOT, -sq4.y));
      sa0[q*4+2] = exp2f_fast(fmaf(sa0[q*4+2], CDOT, -sq4.z));
      sa0[q*4+3] = exp2f_fast(fmaf(sa0[q*4+3], CDOT, -sq4.w));
      sa1[q*4+0] = exp2f_fast(fmaf(sa1[q*4+0], CDOT, -sq4.x));
      sa1[q*4+1] = exp2f_fast(fmaf(sa1[q*4+1], CDOT, -sq4.y));
      sa1[q*4+2] = exp2f_fast(fmaf(sa1[q*4+2], CDOT, -sq4.z));
      sa1[q*4+3] = exp2f_fast(fmaf(sa1[q*4+3], CDOT, -sq4.w));
    }
    if (partial) {
      #pragma unroll
      for (int r = 0; r < 16; ++r) {
        int j = jb + h * 32 + (r & 3) + 8 * (r >> 2) + 4 * hi;
        if (j >= nv2) { sa0[r] = 0.f; sa1[r] = 0.f; }
      }
    }
    #pragma unroll
    for (int r = 0; r < 16; ++r) {
      float jc = (float)(jb + h * 32 + (r & 3) + 8 * (r >> 2) + 4 * hi);
      l2s[0] += sa0[r];
      l2s[1] += sa1[r];
      ixs[0] = fmaf(sa0[r], jc, ixs[0]);
      ixs[1] = fmaf(sa1[r], jc, ixs[1]);
    }

    asm volatile("s_waitcnt vmcnt(0)" ::: "memory");
    __syncthreads();
    cur ^= 1;
  }

  // ---- pair-merge scalars, then per-q loss ----
  RED[w][0][l] = l2s[0]; RED[w][1][l] = l2s[1];
  RED[w][2][l] = ixs[0]; RED[w][3][l] = ixs[1];
  __syncthreads();
  l2s[0] += RED[w ^ 1][0][l]; l2s[1] += RED[w ^ 1][1][l];
  ixs[0] += RED[w ^ 1][2][l]; ixs[1] += RED[w ^ 1][3][l];

  float acc = 0.f;
  #pragma unroll
  for (int s = 0; s < 2; ++s) {
    l2s[s] += __shfl_xor(l2s[s], 32);
    ixs[s] += __shfl_xor(ixs[s], 32);
    int iabs = qh * 128 + p * 64 + s * 32 + il;
    float diff = ixs[s] / l2s[s] - (float)iabs;
    acc += (iabs < nv2) ? diff * diff : 0.f;
  }
  #pragma unroll
  for (int off = 1; off < 32; off <<= 1) acc += __shfl_xor(acc, off);
  if (h == 0 && l == 0)
    partials[cyc * 512 + (b * 8 + qh) * 2 + p] = acc / ((float)nv2 * (float)BATCH);
}

// ---------------- deterministic final reduction ----------------
__global__ void reduce_kernel(const float* __restrict__ partials, float* __restrict__ out) {
  __shared__ float red[256];
  const int c = blockIdx.x;
  float s = 0.f;
  for (int i = threadIdx.x; i < 512; i += 256) s += partials[c * 512 + i];
  red[threadIdx.x] = s;
  __syncthreads();
  for (int off = 128; off > 0; off >>= 1) {
    if (threadIdx.x < off) red[threadIdx.x] += red[threadIdx.x + off];
    __syncthreads();
  }
  if (threadIdx.x == 0) out[c] = red[0];
}

extern "C" void kernel_launch(void* const* d_in, const int* in_sizes, int n_in,
                              void* d_out, int out_size, void* d_ws, size_t ws_size,
                              hipStream_t stream) {
  const float* clip_emb  = (const float*)d_in[0];
  const float* clip_lens = (const float*)d_in[2];
  const float* sent_emb  = (const float*)d_in[3];
  const float* sent_lens = (const float*)d_in[5];
  float* out = (float*)d_out;
  char* wsb = (char*)d_ws;

  char*  embN    = wsb;                                            // 16 MB N tiles
  float* sqe_all = (float*)(wsb + 2 * (size_t)NBLK * TILE_BYTES);  // 64K floats
  float* parts   = sqe_all + 2 * BATCH * SEQ;                      // 1024 floats

  prepack_kernel<<<2 * NBLK, 256, 0, stream>>>(clip_emb, sent_emb, embN, sqe_all);
  cycle_kernel<<<NBLK, 256, 0, stream>>>(embN, sqe_all, clip_lens, sent_lens, parts);
  reduce_kernel<<<2, 256, 0, stream>>>(parts, out);
}